// Round 4
// baseline (1111.351 us; speedup 1.0000x reference)
//
#include <hip/hip_runtime.h>
#include <hip/hip_bf16.h>
#include <float.h>
#include <math.h>

#define NQ    64      // batch / query count
#define DF    256     // feature dim
#define CC    345     // class dim
#define KSF   8       // 256/32 k-steps
#define KSC   11      // ceil(345/32)
#define TPT   2       // tiles (of 32 rows) per dist block
#define EPSN  1e-12f

typedef __attribute__((ext_vector_type(8))) short short8;
typedef __attribute__((ext_vector_type(4))) float f32x4;

// ---------------- block-wide reductions -----------------------------------
__device__ __forceinline__ float blockReduceSum(float v, float* sbuf) {
  __syncthreads();
  #pragma unroll
  for (int o = 32; o > 0; o >>= 1) v += __shfl_down(v, o);
  int w = threadIdx.x >> 6;
  if ((threadIdx.x & 63) == 0) sbuf[w] = v;
  __syncthreads();
  if (threadIdx.x == 0) {
    float s = 0.f;
    int nw = blockDim.x >> 6;
    for (int i = 0; i < nw; ++i) s += sbuf[i];
    sbuf[0] = s;
  }
  __syncthreads();
  return sbuf[0];
}

__device__ __forceinline__ float blockReduceMax(float v, float* sbuf) {
  __syncthreads();
  #pragma unroll
  for (int o = 32; o > 0; o >>= 1) v = fmaxf(v, __shfl_down(v, o));
  int w = threadIdx.x >> 6;
  if ((threadIdx.x & 63) == 0) sbuf[w] = v;
  __syncthreads();
  if (threadIdx.x == 0) {
    float s = -FLT_MAX;
    int nw = blockDim.x >> 6;
    for (int i = 0; i < nw; ++i) s = fmaxf(s, sbuf[i]);
    sbuf[0] = s;
  }
  __syncthreads();
  return sbuf[0];
}

// ------------- top-k insert, list sorted (value desc, index asc) ----------
template<int T>
__device__ __forceinline__ void topk_insert(float v, int id, float (&lv)[T], int (&li)[T]) {
  if (!((v > lv[T-1]) || (v == lv[T-1] && id < li[T-1]))) return;
  #pragma unroll
  for (int p = T-1; p > 0; --p) {
    bool up = (v > lv[p-1]) || (v == lv[p-1] && id < li[p-1]);
    if (up) { lv[p] = lv[p-1]; li[p] = li[p-1]; }
    else    { lv[p] = v; li[p] = id; return; }
  }
  lv[0] = v; li[0] = id;
}

template<int T>
__device__ __forceinline__ void merge4(const float* sv, const int* si, int t,
                                       float* dv, int* di) {
  float fv[T]; int fi[T];
  #pragma unroll
  for (int i = 0; i < T; ++i) { fv[i] = -FLT_MAX; fi[i] = 0x7fffffff; }
  for (int s = 0; s < 4; ++s)
    #pragma unroll
    for (int i = 0; i < T; ++i)
      topk_insert<T>(sv[(t*4+s)*T+i], si[(t*4+s)*T+i], fv, fi);
  #pragma unroll
  for (int i = 0; i < T; ++i) { dv[t*T+i] = fv[i]; di[t*T+i] = fi[i]; }
}

// ---------------- rowmap fill ---------------------------------------------
__global__ void fill_rowmap(int* rowmap, int n) {
  int i = blockIdx.x * blockDim.x + threadIdx.x;
  if (i < n) rowmap[i] = -1;
}

// -------- prep: softmax, normalize queries -> MFMA A-frag pack, updates ---
__global__ __launch_bounds__(384) void prep_kernel(
    const float* __restrict__ tf, const float* __restrict__ fc1,
    const float* __restrict__ fc2, const int* __restrict__ idx,
    const float* __restrict__ featm, const float* __restrict__ fc1m,
    const float* __restrict__ fc2m,
    short* __restrict__ Qp_feat,   // [4][KSF][64][8] bf16 A-fragments
    short* __restrict__ Qp_fc1,    // [4][KSC][64][8]
    short* __restrict__ Qp_fc2,
    float* __restrict__ featU, float* __restrict__ fc1U, float* __restrict__ fc2U,
    int* __restrict__ rowmap)
{
  __shared__ float sbuf[8];
  const int b = blockIdx.x, t = threadIdx.x;
  const int trow = idx[b];
  const int qt = b >> 4, qr = b & 15;

  // ---- feature ----
  {
    float x = (t < DF) ? tf[b*DF + t] : 0.f;
    float ss = blockReduceSum(x*x, sbuf);
    float inv = 1.f / fmaxf(sqrtf(ss), EPSN);
    if (t < DF) {
      featU[b*DF + t] = 0.9f * featm[(size_t)trow*DF + t] + 0.1f * x;
      int ks = t >> 5, lg = (t >> 3) & 3, j = t & 7;
      int lane = qr + lg*16;
      union { __hip_bfloat16 h; short s; } cv;
      cv.h = __float2bfloat16(x * inv);
      Qp_feat[((qt*KSF + ks)*64 + lane)*8 + j] = cv.s;
    }
  }
  // ---- fc1 ----
  {
    float y = (t < CC) ? fc1[b*CC + t] : -FLT_MAX;
    float mx = blockReduceMax(y, sbuf);
    float e = (t < CC) ? expf(y - mx) : 0.f;
    float se = blockReduceSum(e, sbuf);
    float s = e / se;
    float s2 = blockReduceSum(s*s, sbuf);
    float inv2 = 1.f / fmaxf(sqrtf(s2), EPSN);
    if (t < CC) fc1U[b*CC + t] = 0.9f * fc1m[(size_t)trow*CC + t] + 0.1f * s;
    if (t < KSC*32) {
      int ks = t >> 5, lg = (t >> 3) & 3, j = t & 7;
      int lane = qr + lg*16;
      union { __hip_bfloat16 h; short s; } cv;
      cv.h = __float2bfloat16((t < CC) ? s * inv2 : 0.f);
      Qp_fc1[((qt*KSC + ks)*64 + lane)*8 + j] = cv.s;
    }
  }
  // ---- fc2 ----
  {
    float y = (t < CC) ? fc2[b*CC + t] : -FLT_MAX;
    float mx = blockReduceMax(y, sbuf);
    float e = (t < CC) ? expf(y - mx) : 0.f;
    float se = blockReduceSum(e, sbuf);
    float s = e / se;
    float s2 = blockReduceSum(s*s, sbuf);
    float inv2 = 1.f / fmaxf(sqrtf(s2), EPSN);
    if (t < CC) fc2U[b*CC + t] = 0.9f * fc2m[(size_t)trow*CC + t] + 0.1f * s;
    if (t < KSC*32) {
      int ks = t >> 5, lg = (t >> 3) & 3, j = t & 7;
      int lane = qr + lg*16;
      union { __hip_bfloat16 h; short s; } cv;
      cv.h = __float2bfloat16((t < CC) ? s * inv2 : 0.f);
      Qp_fc2[((qt*KSC + ks)*64 + lane)*8 + j] = cv.s;
    }
  }
  if (t == 0) rowmap[trow] = b;
}

// -------- staged MFMA cos-sim v3: single buffer, in-lane norms ------------
// Each block: TPT tiles of 32 rows. 256 threads / 4 waves (16 queries each).
// Staging: row-aligned 16B chunks -> packed bf16 ds_write_b64 into padded LDS.
// Norms fused into fragment unpack (in-lane rinv, no extra barrier).
template<int D, int KS, int T, bool CORR>
__global__ __launch_bounds__(256, 4) void dist_topk3(
    const float* __restrict__ bank,
    const int* __restrict__ rowmap,
    const int* __restrict__ ids,
    const short8* __restrict__ Qp,
    float* __restrict__ cand_v, int* __restrict__ cand_i,
    int ntiles, int cand_cols)
{
  constexpr int RB    = D * 4;                       // global row bytes (f32)
  constexpr int CCR   = (D % 4 == 0) ? D/4 : D/4+1;  // 16B chunks per row (64/87)
  constexpr int FULLC = D / 4;                       // full chunks (64/86)
  constexpr int NCH   = 32 * CCR;
  constexpr int CPI   = (NCH + 255) / 256;
  constexpr int SROW  = (D == 256) ? 528 : 720;      // LDS row stride bytes
  constexpr int KPAD  = KS * 32;
  constexpr int BUFB  = 32 * SROW;

  __shared__ __align__(16) char smem[BUFB + 64*35*4];
  char*  bb   = smem;
  float* sims = (float*)(smem + BUFB);
  float* mv   = (float*)smem;                        // aliased after loop
  int*   mi   = (int*)(smem + 256*T*4);

  const int t  = threadIdx.x;
  const int l  = t & 63, w = t >> 6;
  const int lc = l & 15, lg = l >> 4;
  const int tile0 = CORR ? 0 : blockIdx.x * ntiles;

  // A fragments: wave w's 16 queries
  short8 afr[KS];
  #pragma unroll
  for (int ks = 0; ks < KS; ++ks) afr[ks] = Qp[(w*KS + ks)*64 + l];

  float lv[T]; int li[T];
  #pragma unroll
  for (int i = 0; i < T; ++i) { lv[i] = -FLT_MAX; li[i] = 0x7fffffff; }

  auto STAGE = [&](int tile) {
    const char* tb = (const char*)bank + (size_t)tile * (size_t)(32 * RB);
    #pragma unroll
    for (int i = 0; i < CPI; ++i) {
      int c = t + 256*i;
      if (NCH % 256 != 0 && c >= NCH) break;
      int row = c / CCR, cc = c - row*CCR;
      const char* src = tb + row*RB + cc*16;
      char* dst = bb + row*SROW + cc*8;
      if (CCR == FULLC || cc < FULLC) {
        float4 v = *(const float4*)src;
        union { __hip_bfloat162 h; unsigned u; } p0, p1;
        p0.h = __float22bfloat162_rn(make_float2(v.x, v.y));
        p1.h = __float22bfloat162_rn(make_float2(v.z, v.w));
        *(uint2*)dst = make_uint2(p0.u, p1.u);
      } else {
        // partial last chunk (fc: col D-1 only region)
        float x = *(const float*)src;
        *(__hip_bfloat16*)dst = __float2bfloat16(x);
      }
    }
  };

  // zero k-pad columns once (never overwritten by STAGE)
  if (KPAD > D) {
    for (int z = t; z < 32*(KPAD - D); z += 256) {
      int row = z / (KPAD - D), e = z - row*(KPAD - D);
      *(__hip_bfloat16*)(bb + row*SROW + (D + e)*2) = __float2bfloat16(0.f);
    }
  }
  STAGE(tile0);
  __syncthreads();

  for (int it = 0; it < ntiles; ++it) {
    f32x4 acc[2];
    acc[0] = (f32x4){0.f,0.f,0.f,0.f};
    acc[1] = (f32x4){0.f,0.f,0.f,0.f};
    float sq[2] = {0.f, 0.f};

    #pragma unroll
    for (int ks = 0; ks < KS; ++ks) {
      #pragma unroll
      for (int rt = 0; rt < 2; ++rt) {
        short8 bf = *(const short8*)(bb + (rt*16 + lc)*SROW + ks*64 + lg*16);
        #pragma unroll
        for (int j = 0; j < 8; ++j) {
          float f = __uint_as_float(((unsigned)(unsigned short)bf[j]) << 16);
          sq[rt] += f * f;
        }
        acc[rt] = __builtin_amdgcn_mfma_f32_16x16x32_bf16(afr[ks], bf, acc[rt], 0, 0, 0);
      }
    }

    // in-lane row rinv: lanes lc, lc+16, lc+32, lc+48 hold k-slice partials
    #pragma unroll
    for (int rt = 0; rt < 2; ++rt) {
      float s = sq[rt];
      s += __shfl_xor(s, 16);
      s += __shfl_xor(s, 32);
      float ri = 1.f / fmaxf(sqrtf(s), EPSN);
      #pragma unroll
      for (int rg = 0; rg < 4; ++rg)
        sims[(w*16 + lg*4 + rg)*35 + rt*16 + lc] = acc[rt][rg] * ri;
    }
    __syncthreads();

    // fused topk: 4 threads per query, 8 rows each
    {
      int q = t & 63, sub = t >> 6;
      int g0 = (tile0 + it) * 32;
      #pragma unroll
      for (int j = 0; j < 8; ++j) {
        int col = sub*8 + j;
        float v = sims[q*35 + col];
        int gl = g0 + col;
        if (CORR) topk_insert<T>(v, ids[gl], lv, li);
        else if (rowmap[gl] < 0) topk_insert<T>(v, gl, lv, li);
      }
    }
    if (it + 1 < ntiles) STAGE(tile0 + it + 1);
    __syncthreads();
  }

  // block merge: 4 sublists per query -> candidate slot
  #pragma unroll
  for (int i = 0; i < T; ++i) { mv[t*T + i] = lv[i]; mi[t*T + i] = li[i]; }
  __syncthreads();
  if (t < 64) {
    float fv[T]; int fi[T];
    #pragma unroll
    for (int i = 0; i < T; ++i) { fv[i] = -FLT_MAX; fi[i] = 0x7fffffff; }
    for (int s = 0; s < 4; ++s) {
      int src = t + 64*s;
      #pragma unroll
      for (int i = 0; i < T; ++i)
        topk_insert<T>(mv[src*T + i], mi[src*T + i], fv, fi);
    }
    int slot = CORR ? (cand_cols - 1) : blockIdx.x;
    size_t base = ((size_t)t * cand_cols + slot) * T;
    #pragma unroll
    for (int i = 0; i < T; ++i) { cand_v[base + i] = fv[i]; cand_i[base + i] = fi[i]; }
  }
}

// -------- merge stage 1: 8 blocks per query ------------------------------
template<int T>
__global__ __launch_bounds__(256) void merge_stage1(
    const float* __restrict__ cv, const int* __restrict__ ci,
    int nc, float* __restrict__ midv, int* __restrict__ midi)
{
  __shared__ float sv[256*T]; __shared__ int si[256*T];
  __shared__ float sv2[64*T]; __shared__ int si2[64*T];
  const int q = blockIdx.x >> 3, t = threadIdx.x;
  const int s = blockIdx.x & 7;
  const int len = (nc + 7) >> 3;
  const int lo = s*len, hi = min(nc, lo + len);
  float lv[T]; int li[T];
  #pragma unroll
  for (int i = 0; i < T; ++i) { lv[i] = -FLT_MAX; li[i] = 0x7fffffff; }
  const float* v  = cv + (size_t)q * nc;
  const int*   ii = ci + (size_t)q * nc;
  for (int c = lo + t; c < hi; c += 256) topk_insert<T>(v[c], ii[c], lv, li);
  #pragma unroll
  for (int i = 0; i < T; ++i) { sv[t*T+i] = lv[i]; si[t*T+i] = li[i]; }
  __syncthreads();
  if (t < 64) merge4<T>(sv, si, t, sv2, si2);
  __syncthreads();
  if (t < 16) merge4<T>(sv2, si2, t, sv, si);
  __syncthreads();
  if (t < 4)  merge4<T>(sv, si, t, sv2, si2);
  __syncthreads();
  if (t == 0) {
    float fv[T]; int fi[T];
    #pragma unroll
    for (int i = 0; i < T; ++i) { fv[i] = -FLT_MAX; fi[i] = 0x7fffffff; }
    for (int c = 0; c < 4*T; ++c) topk_insert<T>(sv2[c], si2[c], fv, fi);
    #pragma unroll
    for (int i = 0; i < T; ++i) {
      midv[blockIdx.x*T + i] = fv[i];
      midi[blockIdx.x*T + i] = fi[i];
    }
  }
}

// -------- merge stage 2: final top-T per query ----------------------------
template<int T>
__global__ __launch_bounds__(64) void merge_stage2(
    const float* __restrict__ midv, const int* __restrict__ midi,
    int* __restrict__ topout)      // stride 6
{
  __shared__ float sv[8*T]; __shared__ int si[8*T];
  const int q = blockIdx.x, t = threadIdx.x;
  if (t < 8*T) { sv[t] = midv[q*8*T + t]; si[t] = midi[q*8*T + t]; }
  __syncthreads();
  if (t == 0) {
    float fv[T]; int fi[T];
    #pragma unroll
    for (int i = 0; i < T; ++i) { fv[i] = -FLT_MAX; fi[i] = 0x7fffffff; }
    for (int c = 0; c < 8*T; ++c) topk_insert<T>(sv[c], si[c], fv, fi);
    #pragma unroll
    for (int i = 0; i < T; ++i) topout[q*6 + i] = fi[i];
  }
}

// ---------------- losses ---------------------------------------------------
__global__ __launch_bounds__(384) void loss_softmax_kernel(
    const int* __restrict__ topfeat, const int* __restrict__ rowmap,
    const float* __restrict__ fc1m, const float* __restrict__ fc1U,
    const float* __restrict__ fc2m, const float* __restrict__ fc2U,
    float* __restrict__ out)
{
  __shared__ float sbuf[8];
  int p = blockIdx.x;                // 0..319
  int q = p / 5, j = p % 5 + 1;
  int row = topfeat[q*6 + j];
  int u = rowmap[row];
  const float* r1 = (u >= 0) ? (fc1U + (size_t)u * CC) : (fc1m + (size_t)row * CC);
  const float* r2 = (u >= 0) ? (fc2U + (size_t)u * CC) : (fc2m + (size_t)row * CC);
  int t = threadIdx.x;
  float v = (t < CC) ? fabsf(r1[t] - r2[t]) : 0.f;
  float s = blockReduceSum(v, sbuf);
  if (t == 0) atomicAdd(out, s * (1.f / (320.f * 345.f)));
}

__global__ __launch_bounds__(256) void loss_feature_kernel(
    const int* __restrict__ topfc1, const int* __restrict__ topfc2,
    const int* __restrict__ rowmap, const float* __restrict__ featm,
    const float* __restrict__ featU, float* __restrict__ out)
{
  __shared__ float sbuf[8];
  int p = blockIdx.x;                // 0..255
  int q = p / 4, j = p % 4 + 1;
  int ra = topfc1[q*6 + j], rb = topfc2[q*6 + j];
  int ua = rowmap[ra], ub = rowmap[rb];
  const float* A  = (ua >= 0) ? (featU + (size_t)ua * DF) : (featm + (size_t)ra * DF);
  const float* Bp = (ub >= 0) ? (featU + (size_t)ub * DF) : (featm + (size_t)rb * DF);
  int t = threadIdx.x;               // 256 == DF
  float a = A[t], b = Bp[t];
  float saa = blockReduceSum(a*a, sbuf);
  float sbb = blockReduceSum(b*b, sbuf);
  float sab = blockReduceSum(a*b, sbuf);
  if (t == 0) {
    float fd = 0.5f * (1.f - sab / (fmaxf(sqrtf(saa), EPSN) * fmaxf(sqrtf(sbb), EPSN)));
    atomicAdd(out + 1, fd * (1.f / 256.f));
  }
}

// ---------------- launch ---------------------------------------------------
extern "C" void kernel_launch(void* const* d_in, const int* in_sizes, int n_in,
                              void* d_out, int out_size, void* d_ws, size_t ws_size,
                              hipStream_t stream)
{
  const float* tf    = (const float*)d_in[0];
  const float* fc1   = (const float*)d_in[1];
  const float* fc2   = (const float*)d_in[2];
  const int*   idx   = (const int*)d_in[3];
  const float* featm = (const float*)d_in[4];
  const float* fc1m  = (const float*)d_in[5];
  const float* fc2m  = (const float*)d_in[6];
  float* out = (float*)d_out;

  const int N = in_sizes[4] / DF;          // 200000
  const int NB = N / (32 * TPT);           // 3125 dist blocks
  const int CAND_COLS = NB + 1;            // +1 slot for correction kernel

  char* w = (char*)d_ws;
  auto alloc = [&](size_t bytes) {
    char* p = w;
    w += (bytes + 255) & ~(size_t)255;
    return (void*)p;
  };
  short* Qp_feat = (short*)alloc((size_t)4 * KSF * 64 * 8 * 2);
  short* Qp_fc1  = (short*)alloc((size_t)4 * KSC * 64 * 8 * 2);
  short* Qp_fc2  = (short*)alloc((size_t)4 * KSC * 64 * 8 * 2);
  float* featU   = (float*)alloc((size_t)NQ * DF * 4);
  float* fc1U    = (float*)alloc((size_t)NQ * CC * 4);
  float* fc2U    = (float*)alloc((size_t)NQ * CC * 4);
  int*   rowmap  = (int*)alloc((size_t)N * 4);
  int*   topfeat = (int*)alloc(NQ * 6 * 4);
  int*   topfc1  = (int*)alloc(NQ * 6 * 4);
  int*   topfc2  = (int*)alloc(NQ * 6 * 4);
  float* cand_v  = (float*)alloc((size_t)NQ * CAND_COLS * 6 * 4);
  int*   cand_i  = (int*)alloc((size_t)NQ * CAND_COLS * 6 * 4);
  float* midv    = (float*)alloc((size_t)NQ * 8 * 6 * 4);
  int*   midi    = (int*)alloc((size_t)NQ * 8 * 6 * 4);

  hipMemsetAsync(d_out, 0, 2 * sizeof(float), stream);
  fill_rowmap<<<(N + 255) / 256, 256, 0, stream>>>(rowmap, N);
  prep_kernel<<<NQ, 384, 0, stream>>>(tf, fc1, fc2, idx, featm, fc1m, fc2m,
      Qp_feat, Qp_fc1, Qp_fc2, featU, fc1U, fc2U, rowmap);

  // feature: top-6 (drop first, keep 5)
  dist_topk3<DF, KSF, 6, false><<<NB, 256, 0, stream>>>(
      featm, rowmap, idx, (const short8*)Qp_feat, cand_v, cand_i, TPT, CAND_COLS);
  dist_topk3<DF, KSF, 6, true><<<1, 256, 0, stream>>>(
      featU, rowmap, idx, (const short8*)Qp_feat, cand_v, cand_i, 2, CAND_COLS);
  merge_stage1<6><<<NQ*8, 256, 0, stream>>>(cand_v, cand_i, CAND_COLS*6, midv, midi);
  merge_stage2<6><<<NQ, 64, 0, stream>>>(midv, midi, topfeat);

  // fc1: top-5 (drop first, keep 4)
  dist_topk3<CC, KSC, 5, false><<<NB, 256, 0, stream>>>(
      fc1m, rowmap, idx, (const short8*)Qp_fc1, cand_v, cand_i, TPT, CAND_COLS);
  dist_topk3<CC, KSC, 5, true><<<1, 256, 0, stream>>>(
      fc1U, rowmap, idx, (const short8*)Qp_fc1, cand_v, cand_i, 2, CAND_COLS);
  merge_stage1<5><<<NQ*8, 256, 0, stream>>>(cand_v, cand_i, CAND_COLS*5, midv, midi);
  merge_stage2<5><<<NQ, 64, 0, stream>>>(midv, midi, topfc1);

  // fc2: top-5
  dist_topk3<CC, KSC, 5, false><<<NB, 256, 0, stream>>>(
      fc2m, rowmap, idx, (const short8*)Qp_fc2, cand_v, cand_i, TPT, CAND_COLS);
  dist_topk3<CC, KSC, 5, true><<<1, 256, 0, stream>>>(
      fc2U, rowmap, idx, (const short8*)Qp_fc2, cand_v, cand_i, 2, CAND_COLS);
  merge_stage1<5><<<NQ*8, 256, 0, stream>>>(cand_v, cand_i, CAND_COLS*5, midv, midi);
  merge_stage2<5><<<NQ, 64, 0, stream>>>(midv, midi, topfc2);

  loss_softmax_kernel<<<320, 384, 0, stream>>>(topfeat, rowmap, fc1m, fc1U, fc2m, fc2U, out);
  loss_feature_kernel<<<256, 256, 0, stream>>>(topfc1, topfc2, rowmap, featm, featU, out);
}

// Round 6
// 946.138 us; speedup vs baseline: 1.1746x; 1.1746x over previous
//
#include <hip/hip_runtime.h>
#include <hip/hip_bf16.h>
#include <float.h>
#include <math.h>

#define NQ    64
#define DF    256
#define CC    345
#define KSF   8      // 256/32
#define KSC   11     // ceil(345/32)
#define TPT   2      // tiles of 32 rows per dist block
#define FRESH (1 << 30)
#define EPSN  1e-12f

typedef __attribute__((ext_vector_type(8))) short short8;
typedef __attribute__((ext_vector_type(4))) float f32x4;

// ---------------- block-wide reductions -----------------------------------
__device__ __forceinline__ float blockReduceSum(float v, float* sbuf) {
  __syncthreads();
  #pragma unroll
  for (int o = 32; o > 0; o >>= 1) v += __shfl_down(v, o);
  int w = threadIdx.x >> 6;
  if ((threadIdx.x & 63) == 0) sbuf[w] = v;
  __syncthreads();
  if (threadIdx.x == 0) {
    float s = 0.f;
    int nw = blockDim.x >> 6;
    for (int i = 0; i < nw; ++i) s += sbuf[i];
    sbuf[0] = s;
  }
  __syncthreads();
  return sbuf[0];
}

__device__ __forceinline__ float blockReduceMax(float v, float* sbuf) {
  __syncthreads();
  #pragma unroll
  for (int o = 32; o > 0; o >>= 1) v = fmaxf(v, __shfl_down(v, o));
  int w = threadIdx.x >> 6;
  if ((threadIdx.x & 63) == 0) sbuf[w] = v;
  __syncthreads();
  if (threadIdx.x == 0) {
    float s = -FLT_MAX;
    int nw = blockDim.x >> 6;
    for (int i = 0; i < nw; ++i) s = fmaxf(s, sbuf[i]);
    sbuf[0] = s;
  }
  __syncthreads();
  return sbuf[0];
}

// ------------- top-k insert, list sorted (value desc, index asc) ----------
template<int T>
__device__ __forceinline__ void topk_insert(float v, int id, float (&lv)[T], int (&li)[T]) {
  if (!((v > lv[T-1]) || (v == lv[T-1] && id < li[T-1]))) return;
  #pragma unroll
  for (int p = T-1; p > 0; --p) {
    bool up = (v > lv[p-1]) || (v == lv[p-1] && id < li[p-1]);
    if (up) { lv[p] = lv[p-1]; li[p] = li[p-1]; }
    else    { lv[p] = v; li[p] = id; return; }
  }
  lv[0] = v; li[0] = id;
}

template<int T>
__device__ __forceinline__ void merge4(const float* sv, const int* si, int t,
                                       float* dv, int* di) {
  float fv[T]; int fi[T];
  #pragma unroll
  for (int i = 0; i < T; ++i) { fv[i] = -FLT_MAX; fi[i] = 0x7fffffff; }
  for (int s = 0; s < 4; ++s)
    #pragma unroll
    for (int i = 0; i < T; ++i)
      topk_insert<T>(sv[(t*4+s)*T+i], si[(t*4+s)*T+i], fv, fi);
  #pragma unroll
  for (int i = 0; i < T; ++i) { dv[t*T+i] = fv[i]; di[t*T+i] = fi[i]; }
}

// ---------------- rowmap fill ---------------------------------------------
__global__ void fill_rowmap(int* rowmap, int n) {
  int i = blockIdx.x * blockDim.x + threadIdx.x;
  if (i < n) rowmap[i] = -1;
}

// -------- prep: softmax, normalize queries -> MFMA A-frag pack, updates ---
__global__ __launch_bounds__(384) void prep_kernel(
    const float* __restrict__ tf, const float* __restrict__ fc1,
    const float* __restrict__ fc2, const int* __restrict__ idx,
    const float* __restrict__ featm, const float* __restrict__ fc1m,
    const float* __restrict__ fc2m,
    short* __restrict__ Qp_feat, short* __restrict__ Qp_fc1, short* __restrict__ Qp_fc2,
    float* __restrict__ featU, float* __restrict__ fc1U, float* __restrict__ fc2U,
    int* __restrict__ rowmap)
{
  __shared__ float sbuf[8];
  const int b = blockIdx.x, t = threadIdx.x;
  const int trow = idx[b];
  const int qt = b >> 4, qr = b & 15;

  {
    float x = (t < DF) ? tf[b*DF + t] : 0.f;
    float ss = blockReduceSum(x*x, sbuf);
    float inv = 1.f / fmaxf(sqrtf(ss), EPSN);
    if (t < DF) {
      featU[b*DF + t] = 0.9f * featm[(size_t)trow*DF + t] + 0.1f * x;
      int ks = t >> 5, lg = (t >> 3) & 3, j = t & 7;
      int lane = qr + lg*16;
      union { __hip_bfloat16 h; short s; } cv;
      cv.h = __float2bfloat16(x * inv);
      Qp_feat[((qt*KSF + ks)*64 + lane)*8 + j] = cv.s;
    }
  }
  {
    float y = (t < CC) ? fc1[b*CC + t] : -FLT_MAX;
    float mx = blockReduceMax(y, sbuf);
    float e = (t < CC) ? expf(y - mx) : 0.f;
    float se = blockReduceSum(e, sbuf);
    float s = e / se;
    float s2 = blockReduceSum(s*s, sbuf);
    float inv2 = 1.f / fmaxf(sqrtf(s2), EPSN);
    if (t < CC) fc1U[b*CC + t] = 0.9f * fc1m[(size_t)trow*CC + t] + 0.1f * s;
    if (t < KSC*32) {
      int ks = t >> 5, lg = (t >> 3) & 3, j = t & 7;
      int lane = qr + lg*16;
      union { __hip_bfloat16 h; short s; } cv;
      cv.h = __float2bfloat16((t < CC) ? s * inv2 : 0.f);
      Qp_fc1[((qt*KSC + ks)*64 + lane)*8 + j] = cv.s;
    }
  }
  {
    float y = (t < CC) ? fc2[b*CC + t] : -FLT_MAX;
    float mx = blockReduceMax(y, sbuf);
    float e = (t < CC) ? expf(y - mx) : 0.f;
    float se = blockReduceSum(e, sbuf);
    float s = e / se;
    float s2 = blockReduceSum(s*s, sbuf);
    float inv2 = 1.f / fmaxf(sqrtf(s2), EPSN);
    if (t < CC) fc2U[b*CC + t] = 0.9f * fc2m[(size_t)trow*CC + t] + 0.1f * s;
    if (t < KSC*32) {
      int ks = t >> 5, lg = (t >> 3) & 3, j = t & 7;
      int lane = qr + lg*16;
      union { __hip_bfloat16 h; short s; } cv;
      cv.h = __float2bfloat16((t < CC) ? s * inv2 : 0.f);
      Qp_fc2[((qt*KSC + ks)*64 + lane)*8 + j] = cv.s;
    }
  }
  if (t == 0) rowmap[trow] = b;
}

// -------- staged MFMA cos-sim v4: async ISSUE/WRITE split -----------------
// Grid = nmain+1 blocks; last block handles the 64 momentum-updated rows
// (fresh ids flagged with FRESH; stale duplicates filtered in merge).
template<int D, int KS, int T>
__global__ __launch_bounds__(256, 3) void dist_topk4(
    const float* __restrict__ bank, const float* __restrict__ ubank,
    const int* __restrict__ uids, const short8* __restrict__ Qp,
    float* __restrict__ cand_v, int* __restrict__ cand_i, int nmain)
{
  constexpr int RB    = D * 4;
  constexpr int CCR   = (D + 3) / 4;     // 16B chunks per row (64 / 87)
  constexpr int FULLC = D / 4;           // full chunks (64 / 86)
  constexpr int NCH   = 32 * CCR;
  constexpr int CPI   = (NCH + 255) / 256;
  constexpr int SROW  = (D == 256) ? 528 : 720;   // LDS row stride (bytes)
  constexpr int KPAD  = KS * 32;
  constexpr int BUFB  = 32 * SROW;

  __shared__ __align__(16) char smem[BUFB + 64*35*4 + 2*32*4];
  char*  bb   = smem;
  float* sims = (float*)(smem + BUFB);
  float* rsq  = (float*)(smem + BUFB + 64*35*4);  // [2][32]
  float* mv   = (float*)smem;                     // aliased after loop
  int*   mi   = (int*)(smem + 256*T*4);

  const int t  = threadIdx.x, l = t & 63, w = t >> 6;
  const int lc = l & 15, lg = l >> 4;
  const bool corr = (blockIdx.x >= nmain);
  const float* __restrict__ src = corr ? ubank : bank;
  const int tile0 = corr ? 0 : blockIdx.x * TPT;

  // chunk -> (row, col-chunk) decomposition (tile-invariant)
  int rc_r[CPI], rc_c[CPI];
  #pragma unroll
  for (int i = 0; i < CPI; ++i) {
    int c = t + 256*i;
    int r = c / CCR;
    rc_r[i] = r; rc_c[i] = c - r*CCR;
  }

  short8 afr[KS];
  #pragma unroll
  for (int ks = 0; ks < KS; ++ks) afr[ks] = Qp[(w*KS + ks)*64 + l];

  float4 ld[CPI];

  auto ISSUE = [&](int tile) {
    const char* tb = (const char*)src + (size_t)tile * (size_t)(32*RB);
    #pragma unroll
    for (int i = 0; i < CPI; ++i) {
      int c = t + 256*i;
      if (NCH % 256 == 0 || c < NCH) {
        const char* p = tb + rc_r[i]*RB + rc_c[i]*16;
        if (CCR == FULLC || rc_c[i] < FULLC) ld[i] = *(const float4*)p;
        else ld[i].x = *(const float*)p;      // partial tail chunk (fc)
      }
    }
  };

  auto WRITE = [&](int pn) {
    #pragma unroll
    for (int i = 0; i < CPI; ++i) {
      int c = t + 256*i;
      float s = 0.f;
      if (NCH % 256 == 0 || c < NCH) {
        int row = rc_r[i], cc = rc_c[i];
        char* dst = bb + row*SROW + cc*8;
        if (CCR == FULLC || cc < FULLC) {
          float4 v = ld[i];
          union { __hip_bfloat162 h; unsigned u; } p0, p1;
          p0.h = __float22bfloat162_rn(make_float2(v.x, v.y));
          p1.h = __float22bfloat162_rn(make_float2(v.z, v.w));
          *(uint2*)dst = make_uint2(p0.u, p1.u);
          s = v.x*v.x + v.y*v.y + v.z*v.z + v.w*v.w;
        } else {
          float x = ld[i].x;
          *(__hip_bfloat16*)dst = __float2bfloat16(x);
          s = x*x;
        }
      }
      // row sum-of-squares: wave's 64 chunks span <=2 rows
      int c0 = (t & ~63) + 256*i;     // wave's first chunk this i
      int r0 = c0 / CCR;
      if constexpr (CCR == 64) {
        // exactly one row per wave-group, unique writer -> plain store
        #pragma unroll
        for (int off = 1; off < 64; off <<= 1) s += __shfl_xor(s, off);
        if (l == 0 && r0 < 32) rsq[pn*32 + r0] = s;
      } else {
        int bnd = (r0 + 1)*CCR - c0;  // lanes < bnd -> row r0, else r0+1
        float s_lo = (l < bnd) ? s : 0.f;
        float s_hi = (l < bnd) ? 0.f : s;
        #pragma unroll
        for (int off = 1; off < 64; off <<= 1) {
          s_lo += __shfl_xor(s_lo, off);
          s_hi += __shfl_xor(s_hi, off);
        }
        if (l == 0 && r0 < 32) atomicAdd(&rsq[pn*32 + r0], s_lo);
        if (l == 1 && bnd < 64 && r0 + 1 < 32) atomicAdd(&rsq[pn*32 + r0 + 1], s_hi);
      }
    }
  };

  // k-pad columns zeroed once (never overwritten)
  if (KPAD > D) {
    for (int z = t; z < 32*(KPAD - D); z += 256) {
      int row = z / (KPAD - D), e = z - row*(KPAD - D);
      *(__hip_bfloat16*)(bb + row*SROW + (D + e)*2) = __float2bfloat16(0.f);
    }
  }
  if (t < 64) rsq[t] = 0.f;
  ISSUE(tile0);
  __syncthreads();
  WRITE(0);
  ISSUE(tile0 + 1);                     // early issue; drains under tile 0 work
  __syncthreads();

  float lv[T]; int li[T];
  #pragma unroll
  for (int i = 0; i < T; ++i) { lv[i] = -FLT_MAX; li[i] = 0x7fffffff; }

  for (int it = 0; it < TPT; ++it) {
    const int p = it & 1;
    if (t < 32) rsq[(p^1)*32 + t] = 0.f;

    f32x4 acc0 = (f32x4){0.f,0.f,0.f,0.f};
    f32x4 acc1 = (f32x4){0.f,0.f,0.f,0.f};
    #pragma unroll
    for (int ks = 0; ks < KS; ++ks) {
      short8 b0 = *(const short8*)(bb + lc*SROW + ks*64 + lg*16);
      short8 b1 = *(const short8*)(bb + (16 + lc)*SROW + ks*64 + lg*16);
      acc0 = __builtin_amdgcn_mfma_f32_16x16x32_bf16(afr[ks], b0, acc0, 0, 0, 0);
      acc1 = __builtin_amdgcn_mfma_f32_16x16x32_bf16(afr[ks], b1, acc1, 0, 0, 0);
    }
    float ri0 = 1.f / fmaxf(sqrtf(rsq[p*32 + lc]), EPSN);
    float ri1 = 1.f / fmaxf(sqrtf(rsq[p*32 + 16 + lc]), EPSN);
    #pragma unroll
    for (int rg = 0; rg < 4; ++rg) {
      int qrow = w*16 + lg*4 + rg;
      sims[qrow*35 + lc]      = acc0[rg] * ri0;
      sims[qrow*35 + 16 + lc] = acc1[rg] * ri1;
    }
    __syncthreads();

    // per-thread topk: 4 threads per query, 8 rows each (no global reads)
    {
      int q = t & 63, sub = t >> 6;
      #pragma unroll
      for (int j = 0; j < 8; ++j) {
        int col = sub*8 + j;
        float v = sims[q*35 + col];
        int id = corr ? (uids[it*32 + col] | FRESH) : ((tile0 + it)*32 + col);
        topk_insert<T>(v, id, lv, li);
      }
    }
    if (it + 1 < TPT) WRITE(p ^ 1);
    __syncthreads();
  }

  // block merge: 4 sublists per query -> block-major coalesced candidate slot
  #pragma unroll
  for (int i = 0; i < T; ++i) { mv[t*T + i] = lv[i]; mi[t*T + i] = li[i]; }
  __syncthreads();
  if (t < 64) {
    float fv[T]; int fi[T];
    #pragma unroll
    for (int i = 0; i < T; ++i) { fv[i] = -FLT_MAX; fi[i] = 0x7fffffff; }
    for (int s = 0; s < 4; ++s) {
      int srcidx = t + 64*s;
      #pragma unroll
      for (int i = 0; i < T; ++i)
        topk_insert<T>(mv[srcidx*T + i], mi[srcidx*T + i], fv, fi);
    }
    size_t base = ((size_t)blockIdx.x*64 + t)*T;
    #pragma unroll
    for (int i = 0; i < T; ++i) { cand_v[base + i] = fv[i]; cand_i[base + i] = fi[i]; }
  }
}

// -------- merge stage 1: 8 blocks/query; filters stale updated rows -------
template<int T>
__global__ __launch_bounds__(256) void merge_stage1(
    const float* __restrict__ cv, const int* __restrict__ ci,
    const int* __restrict__ rowmap, int nslots,
    float* __restrict__ midv, int* __restrict__ midi)
{
  __shared__ float sv[256*T]; __shared__ int si[256*T];
  __shared__ float sv2[64*T]; __shared__ int si2[64*T];
  const int q = blockIdx.x >> 3, s = blockIdx.x & 7, t = threadIdx.x;
  const int len = (nslots + 7) >> 3;
  const int lo = s*len, hi = min(nslots, lo + len);
  float lv[T]; int li[T];
  #pragma unroll
  for (int i = 0; i < T; ++i) { lv[i] = -FLT_MAX; li[i] = 0x7fffffff; }
  for (int c = lo + t; c < hi; c += 256) {
    size_t base = ((size_t)c*64 + q)*T;
    #pragma unroll
    for (int i = 0; i < T; ++i) {
      int id = ci[base + i];
      if ((id & FRESH) || rowmap[id] < 0)     // fresh flagged, or untouched row
        topk_insert<T>(cv[base + i], id, lv, li);
    }
  }
  #pragma unroll
  for (int i = 0; i < T; ++i) { sv[t*T+i] = lv[i]; si[t*T+i] = li[i]; }
  __syncthreads();
  if (t < 64) merge4<T>(sv, si, t, sv2, si2);
  __syncthreads();
  if (t < 16) merge4<T>(sv2, si2, t, sv, si);
  __syncthreads();
  if (t < 4)  merge4<T>(sv, si, t, sv2, si2);
  __syncthreads();
  if (t == 0) {
    float fv[T]; int fi[T];
    #pragma unroll
    for (int i = 0; i < T; ++i) { fv[i] = -FLT_MAX; fi[i] = 0x7fffffff; }
    for (int c = 0; c < 4*T; ++c) topk_insert<T>(sv2[c], si2[c], fv, fi);
    #pragma unroll
    for (int i = 0; i < T; ++i) {
      midv[blockIdx.x*T + i] = fv[i];
      midi[blockIdx.x*T + i] = fi[i];
    }
  }
}

// -------- merge stage 2: final top-T per query (strip FRESH flag) ---------
template<int T>
__global__ __launch_bounds__(64) void merge_stage2(
    const float* __restrict__ midv, const int* __restrict__ midi,
    int* __restrict__ topout)      // stride 6
{
  __shared__ float sv[8*T]; __shared__ int si[8*T];
  const int q = blockIdx.x, t = threadIdx.x;
  if (t < 8*T) { sv[t] = midv[q*8*T + t]; si[t] = midi[q*8*T + t]; }
  __syncthreads();
  if (t == 0) {
    float fv[T]; int fi[T];
    #pragma unroll
    for (int i = 0; i < T; ++i) { fv[i] = -FLT_MAX; fi[i] = 0x7fffffff; }
    for (int c = 0; c < 8*T; ++c) topk_insert<T>(sv[c], si[c], fv, fi);
    #pragma unroll
    for (int i = 0; i < T; ++i) topout[q*6 + i] = fi[i] & ~FRESH;
  }
}

// ---------------- losses ---------------------------------------------------
__global__ __launch_bounds__(384) void loss_softmax_kernel(
    const int* __restrict__ topfeat, const int* __restrict__ rowmap,
    const float* __restrict__ fc1m, const float* __restrict__ fc1U,
    const float* __restrict__ fc2m, const float* __restrict__ fc2U,
    float* __restrict__ out)
{
  __shared__ float sbuf[8];
  int p = blockIdx.x;                // 0..319
  int q = p / 5, j = p % 5 + 1;
  int row = topfeat[q*6 + j];
  int u = rowmap[row];
  const float* r1 = (u >= 0) ? (fc1U + (size_t)u * CC) : (fc1m + (size_t)row * CC);
  const float* r2 = (u >= 0) ? (fc2U + (size_t)u * CC) : (fc2m + (size_t)row * CC);
  int t = threadIdx.x;
  float v = (t < CC) ? fabsf(r1[t] - r2[t]) : 0.f;
  float s = blockReduceSum(v, sbuf);
  if (t == 0) atomicAdd(out, s * (1.f / (320.f * 345.f)));
}

__global__ __launch_bounds__(256) void loss_feature_kernel(
    const int* __restrict__ topfc1, const int* __restrict__ topfc2,
    const int* __restrict__ rowmap, const float* __restrict__ featm,
    const float* __restrict__ featU, float* __restrict__ out)
{
  __shared__ float sbuf[8];
  int p = blockIdx.x;                // 0..255
  int q = p / 4, j = p % 4 + 1;
  int ra = topfc1[q*6 + j], rb = topfc2[q*6 + j];
  int ua = rowmap[ra], ub = rowmap[rb];
  const float* A  = (ua >= 0) ? (featU + (size_t)ua * DF) : (featm + (size_t)ra * DF);
  const float* Bp = (ub >= 0) ? (featU + (size_t)ub * DF) : (featm + (size_t)rb * DF);
  int t = threadIdx.x;               // 256 == DF
  float a = A[t], b = Bp[t];
  float saa = blockReduceSum(a*a, sbuf);
  float sbb = blockReduceSum(b*b, sbuf);
  float sab = blockReduceSum(a*b, sbuf);
  if (t == 0) {
    float fd = 0.5f * (1.f - sab / (fmaxf(sqrtf(saa), EPSN) * fmaxf(sqrtf(sbb), EPSN)));
    atomicAdd(out + 1, fd * (1.f / 256.f));
  }
}

// ---------------- launch ---------------------------------------------------
extern "C" void kernel_launch(void* const* d_in, const int* in_sizes, int n_in,
                              void* d_out, int out_size, void* d_ws, size_t ws_size,
                              hipStream_t stream)
{
  const float* tf    = (const float*)d_in[0];
  const float* fc1   = (const float*)d_in[1];
  const float* fc2   = (const float*)d_in[2];
  const int*   idx   = (const int*)d_in[3];
  const float* featm = (const float*)d_in[4];
  const float* fc1m  = (const float*)d_in[5];
  const float* fc2m  = (const float*)d_in[6];
  float* out = (float*)d_out;

  const int N  = in_sizes[4] / DF;      // 200000
  const int NB = N / (32 * TPT);        // 3125 main dist blocks
  const int NSLOT = NB + 1;             // +1 = updated-row block

  char* w = (char*)d_ws;
  auto alloc = [&](size_t bytes) {
    char* p = w;
    w += (bytes + 255) & ~(size_t)255;
    return (void*)p;
  };
  short* Qp_feat = (short*)alloc((size_t)4 * KSF * 64 * 8 * 2);
  short* Qp_fc1  = (short*)alloc((size_t)4 * KSC * 64 * 8 * 2);
  short* Qp_fc2  = (short*)alloc((size_t)4 * KSC * 64 * 8 * 2);
  float* featU   = (float*)alloc((size_t)NQ * DF * 4);
  float* fc1U    = (float*)alloc((size_t)NQ * CC * 4);
  float* fc2U    = (float*)alloc((size_t)NQ * CC * 4);
  int*   rowmap  = (int*)alloc((size_t)N * 4);
  int*   topfeat = (int*)alloc(NQ * 6 * 4);
  int*   topfc1  = (int*)alloc(NQ * 6 * 4);
  int*   topfc2  = (int*)alloc(NQ * 6 * 4);
  float* cand_v  = (float*)alloc((size_t)NSLOT * 64 * 6 * 4);
  int*   cand_i  = (int*)alloc((size_t)NSLOT * 64 * 6 * 4);
  float* midv    = (float*)alloc((size_t)NQ * 8 * 6 * 4);
  int*   midi    = (int*)alloc((size_t)NQ * 8 * 6 * 4);

  hipMemsetAsync(d_out, 0, 2 * sizeof(float), stream);
  fill_rowmap<<<(N + 255) / 256, 256, 0, stream>>>(rowmap, N);
  prep_kernel<<<NQ, 384, 0, stream>>>(tf, fc1, fc2, idx, featm, fc1m, fc2m,
      Qp_feat, Qp_fc1, Qp_fc2, featU, fc1U, fc2U, rowmap);

  // feature: top-6 (drop first, keep 5)
  dist_topk4<DF, KSF, 6><<<NSLOT, 256, 0, stream>>>(
      featm, featU, idx, (const short8*)Qp_feat, cand_v, cand_i, NB);
  merge_stage1<6><<<NQ*8, 256, 0, stream>>>(cand_v, cand_i, rowmap, NSLOT, midv, midi);
  merge_stage2<6><<<NQ, 64, 0, stream>>>(midv, midi, topfeat);

  // fc1: top-5 (drop first, keep 4)
  dist_topk4<CC, KSC, 5><<<NSLOT, 256, 0, stream>>>(
      fc1m, fc1U, idx, (const short8*)Qp_fc1, cand_v, cand_i, NB);
  merge_stage1<5><<<NQ*8, 256, 0, stream>>>(cand_v, cand_i, rowmap, NSLOT, midv, midi);
  merge_stage2<5><<<NQ, 64, 0, stream>>>(midv, midi, topfc1);

  // fc2: top-5
  dist_topk4<CC, KSC, 5><<<NSLOT, 256, 0, stream>>>(
      fc2m, fc2U, idx, (const short8*)Qp_fc2, cand_v, cand_i, NB);
  merge_stage1<5><<<NQ*8, 256, 0, stream>>>(cand_v, cand_i, rowmap, NSLOT, midv, midi);
  merge_stage2<5><<<NQ, 64, 0, stream>>>(midv, midi, topfc2);

  loss_softmax_kernel<<<320, 384, 0, stream>>>(topfeat, rowmap, fc1m, fc1U, fc2m, fc2U, out);
  loss_feature_kernel<<<256, 256, 0, stream>>>(topfc1, topfc2, rowmap, featm, featU, out);
}

// Round 9
// 678.227 us; speedup vs baseline: 1.6386x; 1.3950x over previous
//
#include <hip/hip_runtime.h>
#include <hip/hip_bf16.h>
#include <float.h>
#include <math.h>

#define NQ    64
#define DF    256
#define CC    345
#define KSF   8      // 256/32
#define KSC   11     // ceil(345/32)
#define NBM   768    // main dist blocks (3/CU x 256)
#define FRESH (1 << 30)
#define EPSN  1e-12f

typedef __attribute__((ext_vector_type(8))) short short8;
typedef __attribute__((ext_vector_type(4))) float f32x4;

// ---- global->LDS DMA (CK-style pointer casts; size is a literal) ---------
__device__ __forceinline__ void gld16(const void* g, void* l) {
  __builtin_amdgcn_global_load_lds(
      static_cast<const uint32_t*>(g), static_cast<uint32_t*>(l), 16, 0, 0);
}
__device__ __forceinline__ void gld4(const void* g, void* l) {
  __builtin_amdgcn_global_load_lds(
      static_cast<const uint32_t*>(g), static_cast<uint32_t*>(l), 4, 0, 0);
}

// ---------------- block-wide reductions -----------------------------------
__device__ __forceinline__ float blockReduceSum(float v, float* sbuf) {
  __syncthreads();
  #pragma unroll
  for (int o = 32; o > 0; o >>= 1) v += __shfl_down(v, o);
  int w = threadIdx.x >> 6;
  if ((threadIdx.x & 63) == 0) sbuf[w] = v;
  __syncthreads();
  if (threadIdx.x == 0) {
    float s = 0.f;
    int nw = blockDim.x >> 6;
    for (int i = 0; i < nw; ++i) s += sbuf[i];
    sbuf[0] = s;
  }
  __syncthreads();
  return sbuf[0];
}

__device__ __forceinline__ float blockReduceMax(float v, float* sbuf) {
  __syncthreads();
  #pragma unroll
  for (int o = 32; o > 0; o >>= 1) v = fmaxf(v, __shfl_down(v, o));
  int w = threadIdx.x >> 6;
  if ((threadIdx.x & 63) == 0) sbuf[w] = v;
  __syncthreads();
  if (threadIdx.x == 0) {
    float s = -FLT_MAX;
    int nw = blockDim.x >> 6;
    for (int i = 0; i < nw; ++i) s = fmaxf(s, sbuf[i]);
    sbuf[0] = s;
  }
  __syncthreads();
  return sbuf[0];
}

// ------------- top-k insert, list sorted (value desc, index asc) ----------
template<int T>
__device__ __forceinline__ void topk_insert(float v, int id, float (&lv)[T], int (&li)[T]) {
  if (!((v > lv[T-1]) || (v == lv[T-1] && id < li[T-1]))) return;
  #pragma unroll
  for (int p = T-1; p > 0; --p) {
    bool up = (v > lv[p-1]) || (v == lv[p-1] && id < li[p-1]);
    if (up) { lv[p] = lv[p-1]; li[p] = li[p-1]; }
    else    { lv[p] = v; li[p] = id; return; }
  }
  lv[0] = v; li[0] = id;
}

template<int T>
__device__ __forceinline__ void merge4(const float* sv, const int* si, int t,
                                       float* dv, int* di) {
  float fv[T]; int fi[T];
  #pragma unroll
  for (int i = 0; i < T; ++i) { fv[i] = -FLT_MAX; fi[i] = 0x7fffffff; }
  for (int s = 0; s < 4; ++s)
    #pragma unroll
    for (int i = 0; i < T; ++i)
      topk_insert<T>(sv[(t*4+s)*T+i], si[(t*4+s)*T+i], fv, fi);
  #pragma unroll
  for (int i = 0; i < T; ++i) { dv[t*T+i] = fv[i]; di[t*T+i] = fi[i]; }
}

// ---------------- rowmap fill ---------------------------------------------
__global__ void fill_rowmap(int* rowmap, int n) {
  int i = blockIdx.x * blockDim.x + threadIdx.x;
  if (i < n) rowmap[i] = -1;
}

// -------- prep: softmax, normalize queries -> MFMA A-frag pack, updates ---
__global__ __launch_bounds__(384) void prep_kernel(
    const float* __restrict__ tf, const float* __restrict__ fc1,
    const float* __restrict__ fc2, const int* __restrict__ idx,
    const float* __restrict__ featm, const float* __restrict__ fc1m,
    const float* __restrict__ fc2m,
    short* __restrict__ Qp_feat, short* __restrict__ Qp_fc1, short* __restrict__ Qp_fc2,
    float* __restrict__ featU, float* __restrict__ fc1U, float* __restrict__ fc2U,
    int* __restrict__ rowmap)
{
  __shared__ float sbuf[8];
  const int b = blockIdx.x, t = threadIdx.x;
  const int trow = idx[b];
  const int qt = b >> 4, qr = b & 15;

  {
    float x = (t < DF) ? tf[b*DF + t] : 0.f;
    float ss = blockReduceSum(x*x, sbuf);
    float inv = 1.f / fmaxf(sqrtf(ss), EPSN);
    if (t < DF) {
      featU[b*DF + t] = 0.9f * featm[(size_t)trow*DF + t] + 0.1f * x;
      int ks = t >> 5, lg = (t >> 3) & 3, j = t & 7;
      int lane = qr + lg*16;
      union { __hip_bfloat16 h; short s; } cv;
      cv.h = __float2bfloat16(x * inv);
      Qp_feat[((qt*KSF + ks)*64 + lane)*8 + j] = cv.s;
    }
  }
  {
    float y = (t < CC) ? fc1[b*CC + t] : -FLT_MAX;
    float mx = blockReduceMax(y, sbuf);
    float e = (t < CC) ? expf(y - mx) : 0.f;
    float se = blockReduceSum(e, sbuf);
    float s = e / se;
    float s2 = blockReduceSum(s*s, sbuf);
    float inv2 = 1.f / fmaxf(sqrtf(s2), EPSN);
    if (t < CC) fc1U[b*CC + t] = 0.9f * fc1m[(size_t)trow*CC + t] + 0.1f * s;
    if (t < KSC*32) {
      int ks = t >> 5, lg = (t >> 3) & 3, j = t & 7;
      int lane = qr + lg*16;
      union { __hip_bfloat16 h; short s; } cv;
      cv.h = __float2bfloat16((t < CC) ? s * inv2 : 0.f);
      Qp_fc1[((qt*KSC + ks)*64 + lane)*8 + j] = cv.s;
    }
  }
  {
    float y = (t < CC) ? fc2[b*CC + t] : -FLT_MAX;
    float mx = blockReduceMax(y, sbuf);
    float e = (t < CC) ? expf(y - mx) : 0.f;
    float se = blockReduceSum(e, sbuf);
    float s = e / se;
    float s2 = blockReduceSum(s*s, sbuf);
    float inv2 = 1.f / fmaxf(sqrtf(s2), EPSN);
    if (t < CC) fc2U[b*CC + t] = 0.9f * fc2m[(size_t)trow*CC + t] + 0.1f * s;
    if (t < KSC*32) {
      int ks = t >> 5, lg = (t >> 3) & 3, j = t & 7;
      int lane = qr + lg*16;
      union { __hip_bfloat16 h; short s; } cv;
      cv.h = __float2bfloat16((t < CC) ? s * inv2 : 0.f);
      Qp_fc2[((qt*KSC + ks)*64 + lane)*8 + j] = cv.s;
    }
  }
  if (t == 0) rowmap[trow] = b;
}

// -------- dist v5: global_load_lds DMA staging, 16-row tiles, 2-phase -----
// Main blocks stream many tiles each; 4 trailing blocks handle the 64
// momentum-updated rows (ids flagged FRESH; stale dups filtered in merge).
template<int D, int KS, int T>
__global__ __launch_bounds__(256, 3) void dist_topk5(
    const float* __restrict__ bank, const float* __restrict__ ubank,
    const int* __restrict__ uids, const short8* __restrict__ Qp,
    float* __restrict__ cand_v, int* __restrict__ cand_i,
    int nmain, int ntq, int ntr)
{
  constexpr bool FEAT = (D == 256);
  constexpr int GROW = D * 4;                  // global row bytes: 1024/1380
  constexpr int SROW = FEAT ? 1024 : 1392;     // LDS row stride (16B mult)
  constexpr int BUFB = 16 * SROW;

  __shared__ __align__(16) char smem[2*BUFB + 128 + 2*64*17*4];
  char*  k344 = smem + 2*BUFB;                 // [2][16] f32 (fc k=344)
  float* sims = (float*)(smem + 2*BUFB + 128); // [2][64][17]
  float* mv   = (float*)smem;                  // epilogue alias
  int*   mi   = (int*)(smem + 256*T*4);

  const int t = threadIdx.x, l = t & 63, w = t >> 6;
  const int lc = l & 15, lg = l >> 4;
  const bool corr = ((int)blockIdx.x >= nmain);
  const float* srcb = corr ? ubank : bank;

  int tile0, nt;
  if (corr) { tile0 = blockIdx.x - nmain; nt = 1; }
  else {
    int b = blockIdx.x;
    tile0 = b*ntq + (b < ntr ? b : ntr);
    nt = ntq + (b < ntr ? 1 : 0);
  }

  short8 afr[KS];
  #pragma unroll
  for (int ks = 0; ks < KS; ++ks) afr[ks] = Qp[(w*KS + ks)*64 + l];

  auto STAGE = [&](int tile, int pn) {
    const char* tb = (const char*)srcb + (size_t)tile * (size_t)(16*GROW);
    char* bb = smem + pn*BUFB;
    #pragma unroll
    for (int r2 = 0; r2 < 4; ++r2) {
      int row = w*4 + r2;                      // wave-uniform
      if (FEAT) {
        // pre-swizzled source so swizzled reads see linear data (rule #21)
        gld16(tb + row*1024 + ((l ^ (row & 7)) * 16), bb + row*1024);
      } else {
        gld16(tb + row*1380 + l*16, bb + row*1392);
        if (l < 22) gld16(tb + row*1380 + 1024 + l*16, bb + row*1392 + 1024);
      }
    }
    if (!FEAT && w == 0 && l < 16)
      gld4(tb + l*1380 + 1376, k344 + pn*64);
  };

  STAGE(tile0, 0);
  __syncthreads();                             // drains DMA (vmcnt 0)

  float lv[T]; int li[T];
  #pragma unroll
  for (int i = 0; i < T; ++i) { lv[i] = -FLT_MAX; li[i] = 0x7fffffff; }

  for (int it = 0; it < nt; ++it) {
    const int pn = it & 1;
    if (it + 1 < nt) STAGE(tile0 + it + 1, pn ^ 1);   // DMA flies under compute

    const char* bb = smem + pn*BUFB;
    f32x4 acc = (f32x4){0.f, 0.f, 0.f, 0.f};
    float sq = 0.f;

    #pragma unroll
    for (int ks = 0; ks < KS; ++ks) {
      float v[8];
      if (!FEAT && ks == KS-1 && lg == 3) {    // fc tail: only k=344 valid
        v[0] = *(const float*)(k344 + pn*64 + lc*4);
        #pragma unroll
        for (int j = 1; j < 8; ++j) v[j] = 0.f;
      } else if (FEAT) {
        int g0 = ks*8 + lg*2;
        float4 a = *(const float4*)(bb + lc*1024 + ((g0 ^ (lc & 7)) * 16));
        float4 c = *(const float4*)(bb + lc*1024 + (((g0 + 1) ^ (lc & 7)) * 16));
        v[0]=a.x; v[1]=a.y; v[2]=a.z; v[3]=a.w;
        v[4]=c.x; v[5]=c.y; v[6]=c.z; v[7]=c.w;
      } else {
        const char* p = bb + lc*1392 + ks*128 + lg*32;
        float4 a = *(const float4*)p;
        float4 c = *(const float4*)(p + 16);
        v[0]=a.x; v[1]=a.y; v[2]=a.z; v[3]=a.w;
        v[4]=c.x; v[5]=c.y; v[6]=c.z; v[7]=c.w;
      }
      #pragma unroll
      for (int j = 0; j < 8; ++j) sq += v[j]*v[j];
      union { short8 s8; __hip_bfloat162 h2[4]; } fb;
      #pragma unroll
      for (int j = 0; j < 4; ++j)
        fb.h2[j] = __float22bfloat162_rn(make_float2(v[2*j], v[2*j+1]));
      acc = __builtin_amdgcn_mfma_f32_16x16x32_bf16(afr[ks], fb.s8, acc, 0, 0, 0);
    }

    // in-lane row rinv: lanes lc, lc^16, lc^32, lc^48 hold k-slice partials
    float s = sq;
    s += __shfl_xor(s, 16);
    s += __shfl_xor(s, 32);
    float ri = 1.f / fmaxf(sqrtf(s), EPSN);

    float* sp = sims + pn*64*17;
    #pragma unroll
    for (int rg = 0; rg < 4; ++rg)
      sp[(w*16 + lg*4 + rg)*17 + lc] = acc[rg] * ri;
    __syncthreads();                           // sims ready + next-tile DMA drained

    // topk: 4 threads per query, 4 rows each; no global reads
    {
      int q = t & 63, sub = t >> 6;
      const float* s2 = sims + pn*64*17 + q*17 + sub*4;
      #pragma unroll
      for (int j = 0; j < 4; ++j) {
        int r = sub*4 + j;
        int id = corr ? (uids[tile0*16 + r] | FRESH) : ((tile0 + it)*16 + r);
        topk_insert<T>(s2[j], id, lv, li);
      }
    }
  }
  __syncthreads();                             // all compute done before alias

  // block merge: 4 sublists per query -> block-major coalesced cand slot
  #pragma unroll
  for (int i = 0; i < T; ++i) { mv[t*T + i] = lv[i]; mi[t*T + i] = li[i]; }
  __syncthreads();
  if (t < 64) {
    float fv[T]; int fi[T];
    #pragma unroll
    for (int i = 0; i < T; ++i) { fv[i] = -FLT_MAX; fi[i] = 0x7fffffff; }
    for (int s = 0; s < 4; ++s) {
      int srcidx = t + 64*s;
      #pragma unroll
      for (int i = 0; i < T; ++i)
        topk_insert<T>(mv[srcidx*T + i], mi[srcidx*T + i], fv, fi);
    }
    size_t base = ((size_t)blockIdx.x*64 + t)*T;
    #pragma unroll
    for (int i = 0; i < T; ++i) { cand_v[base + i] = fv[i]; cand_i[base + i] = fi[i]; }
  }
}

// -------- merge stage 1: 8 blocks/query; filters stale updated rows -------
template<int T>
__global__ __launch_bounds__(256) void merge_stage1(
    const float* __restrict__ cv, const int* __restrict__ ci,
    const int* __restrict__ rowmap, int nslots,
    float* __restrict__ midv, int* __restrict__ midi)
{
  __shared__ float sv[256*T]; __shared__ int si[256*T];
  __shared__ float sv2[64*T]; __shared__ int si2[64*T];
  const int q = blockIdx.x >> 3, s = blockIdx.x & 7, t = threadIdx.x;
  const int len = (nslots + 7) >> 3;
  const int lo = s*len, hi = min(nslots, lo + len);
  float lv[T]; int li[T];
  #pragma unroll
  for (int i = 0; i < T; ++i) { lv[i] = -FLT_MAX; li[i] = 0x7fffffff; }
  for (int c = lo + t; c < hi; c += 256) {
    size_t base = ((size_t)c*64 + q)*T;
    #pragma unroll
    for (int i = 0; i < T; ++i) {
      int id = ci[base + i];
      if ((id & FRESH) || rowmap[id] < 0)
        topk_insert<T>(cv[base + i], id, lv, li);
    }
  }
  #pragma unroll
  for (int i = 0; i < T; ++i) { sv[t*T+i] = lv[i]; si[t*T+i] = li[i]; }
  __syncthreads();
  if (t < 64) merge4<T>(sv, si, t, sv2, si2);
  __syncthreads();
  if (t < 16) merge4<T>(sv2, si2, t, sv, si);
  __syncthreads();
  if (t < 4)  merge4<T>(sv, si, t, sv2, si2);
  __syncthreads();
  if (t == 0) {
    float fv[T]; int fi[T];
    #pragma unroll
    for (int i = 0; i < T; ++i) { fv[i] = -FLT_MAX; fi[i] = 0x7fffffff; }
    for (int c = 0; c < 4*T; ++c) topk_insert<T>(sv2[c], si2[c], fv, fi);
    #pragma unroll
    for (int i = 0; i < T; ++i) {
      midv[blockIdx.x*T + i] = fv[i];
      midi[blockIdx.x*T + i] = fi[i];
    }
  }
}

// -------- merge stage 2: final top-T per query (strip FRESH flag) ---------
template<int T>
__global__ __launch_bounds__(64) void merge_stage2(
    const float* __restrict__ midv, const int* __restrict__ midi,
    int* __restrict__ topout)      // stride 6
{
  __shared__ float sv[8*T]; __shared__ int si[8*T];
  const int q = blockIdx.x, t = threadIdx.x;
  if (t < 8*T) { sv[t] = midv[q*8*T + t]; si[t] = midi[q*8*T + t]; }
  __syncthreads();
  if (t == 0) {
    float fv[T]; int fi[T];
    #pragma unroll
    for (int i = 0; i < T; ++i) { fv[i] = -FLT_MAX; fi[i] = 0x7fffffff; }
    for (int c = 0; c < 8*T; ++c) topk_insert<T>(sv[c], si[c], fv, fi);
    #pragma unroll
    for (int i = 0; i < T; ++i) topout[q*6 + i] = fi[i] & ~FRESH;
  }
}

// ---------------- losses ---------------------------------------------------
__global__ __launch_bounds__(384) void loss_softmax_kernel(
    const int* __restrict__ topfeat, const int* __restrict__ rowmap,
    const float* __restrict__ fc1m, const float* __restrict__ fc1U,
    const float* __restrict__ fc2m, const float* __restrict__ fc2U,
    float* __restrict__ out)
{
  __shared__ float sbuf[8];
  int p = blockIdx.x;                // 0..319
  int q = p / 5, j = p % 5 + 1;
  int row = topfeat[q*6 + j];
  int u = rowmap[row];
  const float* r1 = (u >= 0) ? (fc1U + (size_t)u * CC) : (fc1m + (size_t)row * CC);
  const float* r2 = (u >= 0) ? (fc2U + (size_t)u * CC) : (fc2m + (size_t)row * CC);
  int t = threadIdx.x;
  float v = (t < CC) ? fabsf(r1[t] - r2[t]) : 0.f;
  float s = blockReduceSum(v, sbuf);
  if (t == 0) atomicAdd(out, s * (1.f / (320.f * 345.f)));
}

__global__ __launch_bounds__(256) void loss_feature_kernel(
    const int* __restrict__ topfc1, const int* __restrict__ topfc2,
    const int* __restrict__ rowmap, const float* __restrict__ featm,
    const float* __restrict__ featU, float* __restrict__ out)
{
  __shared__ float sbuf[8];
  int p = blockIdx.x;                // 0..255
  int q = p / 4, j = p % 4 + 1;
  int ra = topfc1[q*6 + j], rb = topfc2[q*6 + j];
  int ua = rowmap[ra], ub = rowmap[rb];
  const float* A  = (ua >= 0) ? (featU + (size_t)ua * DF) : (featm + (size_t)ra * DF);
  const float* Bp = (ub >= 0) ? (featU + (size_t)ub * DF) : (featm + (size_t)rb * DF);
  int t = threadIdx.x;               // 256 == DF
  float a = A[t], b = Bp[t];
  float saa = blockReduceSum(a*a, sbuf);
  float sbb = blockReduceSum(b*b, sbuf);
  float sab = blockReduceSum(a*b, sbuf);
  if (t == 0) {
    float fd = 0.5f * (1.f - sab / (fmaxf(sqrtf(saa), EPSN) * fmaxf(sqrtf(sbb), EPSN)));
    atomicAdd(out + 1, fd * (1.f / 256.f));
  }
}

// ---------------- launch ---------------------------------------------------
extern "C" void kernel_launch(void* const* d_in, const int* in_sizes, int n_in,
                              void* d_out, int out_size, void* d_ws, size_t ws_size,
                              hipStream_t stream)
{
  const float* tf    = (const float*)d_in[0];
  const float* fc1   = (const float*)d_in[1];
  const float* fc2   = (const float*)d_in[2];
  const int*   idx   = (const int*)d_in[3];
  const float* featm = (const float*)d_in[4];
  const float* fc1m  = (const float*)d_in[5];
  const float* fc2m  = (const float*)d_in[6];
  float* out = (float*)d_out;

  const int N     = in_sizes[4] / DF;    // 200000
  const int TILES = N / 16;              // 12500
  const int NTQ   = TILES / NBM;         // 16
  const int NTR   = TILES - NTQ * NBM;   // 212
  const int NSLOT = NBM + 4;             // + 4 updated-row blocks

  char* w = (char*)d_ws;
  auto alloc = [&](size_t bytes) {
    char* p = w;
    w += (bytes + 255) & ~(size_t)255;
    return (void*)p;
  };
  short* Qp_feat = (short*)alloc((size_t)4 * KSF * 64 * 8 * 2);
  short* Qp_fc1  = (short*)alloc((size_t)4 * KSC * 64 * 8 * 2);
  short* Qp_fc2  = (short*)alloc((size_t)4 * KSC * 64 * 8 * 2);
  float* featU   = (float*)alloc((size_t)NQ * DF * 4);
  float* fc1U    = (float*)alloc((size_t)NQ * CC * 4);
  float* fc2U    = (float*)alloc((size_t)NQ * CC * 4);
  int*   rowmap  = (int*)alloc((size_t)N * 4);
  int*   topfeat = (int*)alloc(NQ * 6 * 4);
  int*   topfc1  = (int*)alloc(NQ * 6 * 4);
  int*   topfc2  = (int*)alloc(NQ * 6 * 4);
  float* cand_v  = (float*)alloc((size_t)NSLOT * 64 * 6 * 4);
  int*   cand_i  = (int*)alloc((size_t)NSLOT * 64 * 6 * 4);
  float* midv    = (float*)alloc((size_t)NQ * 8 * 6 * 4);
  int*   midi    = (int*)alloc((size_t)NQ * 8 * 6 * 4);

  hipMemsetAsync(d_out, 0, 2 * sizeof(float), stream);
  fill_rowmap<<<(N + 255) / 256, 256, 0, stream>>>(rowmap, N);
  prep_kernel<<<NQ, 384, 0, stream>>>(tf, fc1, fc2, idx, featm, fc1m, fc2m,
      Qp_feat, Qp_fc1, Qp_fc2, featU, fc1U, fc2U, rowmap);

  // feature: top-6 (drop first, keep 5)
  dist_topk5<DF, KSF, 6><<<NSLOT, 256, 0, stream>>>(
      featm, featU, idx, (const short8*)Qp_feat, cand_v, cand_i, NBM, NTQ, NTR);
  merge_stage1<6><<<NQ*8, 256, 0, stream>>>(cand_v, cand_i, rowmap, NSLOT, midv, midi);
  merge_stage2<6><<<NQ, 64, 0, stream>>>(midv, midi, topfeat);

  // fc1: top-5 (drop first, keep 4)
  dist_topk5<CC, KSC, 5><<<NSLOT, 256, 0, stream>>>(
      fc1m, fc1U, idx, (const short8*)Qp_fc1, cand_v, cand_i, NBM, NTQ, NTR);
  merge_stage1<5><<<NQ*8, 256, 0, stream>>>(cand_v, cand_i, rowmap, NSLOT, midv, midi);
  merge_stage2<5><<<NQ, 64, 0, stream>>>(midv, midi, topfc1);

  // fc2: top-5
  dist_topk5<CC, KSC, 5><<<NSLOT, 256, 0, stream>>>(
      fc2m, fc2U, idx, (const short8*)Qp_fc2, cand_v, cand_i, NBM, NTQ, NTR);
  merge_stage1<5><<<NQ*8, 256, 0, stream>>>(cand_v, cand_i, rowmap, NSLOT, midv, midi);
  merge_stage2<5><<<NQ, 64, 0, stream>>>(midv, midi, topfc2);

  loss_softmax_kernel<<<320, 384, 0, stream>>>(topfeat, rowmap, fc1m, fc1U, fc2m, fc2U, out);
  loss_feature_kernel<<<256, 256, 0, stream>>>(topfc1, topfc2, rowmap, featm, featU, out);
}

// Round 10
// 678.067 us; speedup vs baseline: 1.6390x; 1.0002x over previous
//
#include <hip/hip_runtime.h>
#include <hip/hip_bf16.h>
#include <float.h>
#include <math.h>

#define NQ    64
#define DF    256
#define CC    345
#define KSF   8      // 256/32
#define KSC   11     // ceil(345/32)
#define NBM   768    // main dist blocks (3/CU x 256)
#define FRESH (1 << 30)
#define EPSN  1e-12f

typedef __attribute__((ext_vector_type(8))) short short8;
typedef __attribute__((ext_vector_type(4))) float f32x4;

// ---- global->LDS DMA (size is a literal) ---------------------------------
__device__ __forceinline__ void gld16(const void* g, void* l) {
  __builtin_amdgcn_global_load_lds(
      static_cast<const uint32_t*>(g), static_cast<uint32_t*>(l), 16, 0, 0);
}
__device__ __forceinline__ void gld4(const void* g, void* l) {
  __builtin_amdgcn_global_load_lds(
      static_cast<const uint32_t*>(g), static_cast<uint32_t*>(l), 4, 0, 0);
}

// ---- counted waitcnt helpers (literal N; sched fence per rule #18) -------
__device__ __forceinline__ void wait_vm0() {
  asm volatile("s_waitcnt vmcnt(0)" ::: "memory");
  __builtin_amdgcn_sched_barrier(0);
}
__device__ __forceinline__ void wait_vm4() {
  asm volatile("s_waitcnt vmcnt(4)" ::: "memory");
  __builtin_amdgcn_sched_barrier(0);
}
__device__ __forceinline__ void wait_vm8() {
  asm volatile("s_waitcnt vmcnt(8)" ::: "memory");
  __builtin_amdgcn_sched_barrier(0);
}
__device__ __forceinline__ void wait_vm9() {
  asm volatile("s_waitcnt vmcnt(9)" ::: "memory");
  __builtin_amdgcn_sched_barrier(0);
}
__device__ __forceinline__ void wait_lgkm0() {
  asm volatile("s_waitcnt lgkmcnt(0)" ::: "memory");
  __builtin_amdgcn_sched_barrier(0);
}
__device__ __forceinline__ void raw_barrier() {
  __builtin_amdgcn_sched_barrier(0);
  __builtin_amdgcn_s_barrier();
  __builtin_amdgcn_sched_barrier(0);
}

// ---------------- zero d_out ----------------------------------------------
__global__ void zero_out(float* out) {
  if (threadIdx.x < 2) out[threadIdx.x] = 0.f;
}

// ---------------- block-wide reductions -----------------------------------
__device__ __forceinline__ float blockReduceSum(float v, float* sbuf) {
  __syncthreads();
  #pragma unroll
  for (int o = 32; o > 0; o >>= 1) v += __shfl_down(v, o);
  int w = threadIdx.x >> 6;
  if ((threadIdx.x & 63) == 0) sbuf[w] = v;
  __syncthreads();
  if (threadIdx.x == 0) {
    float s = 0.f;
    int nw = blockDim.x >> 6;
    for (int i = 0; i < nw; ++i) s += sbuf[i];
    sbuf[0] = s;
  }
  __syncthreads();
  return sbuf[0];
}

__device__ __forceinline__ float blockReduceMax(float v, float* sbuf) {
  __syncthreads();
  #pragma unroll
  for (int o = 32; o > 0; o >>= 1) v = fmaxf(v, __shfl_down(v, o));
  int w = threadIdx.x >> 6;
  if ((threadIdx.x & 63) == 0) sbuf[w] = v;
  __syncthreads();
  if (threadIdx.x == 0) {
    float s = -FLT_MAX;
    int nw = blockDim.x >> 6;
    for (int i = 0; i < nw; ++i) s = fmaxf(s, sbuf[i]);
    sbuf[0] = s;
  }
  __syncthreads();
  return sbuf[0];
}

// ------------- top-k insert, list sorted (value desc, index asc) ----------
template<int T>
__device__ __forceinline__ void topk_insert(float v, int id, float (&lv)[T], int (&li)[T]) {
  if (!((v > lv[T-1]) || (v == lv[T-1] && id < li[T-1]))) return;
  #pragma unroll
  for (int p = T-1; p > 0; --p) {
    bool up = (v > lv[p-1]) || (v == lv[p-1] && id < li[p-1]);
    if (up) { lv[p] = lv[p-1]; li[p] = li[p-1]; }
    else    { lv[p] = v; li[p] = id; return; }
  }
  lv[0] = v; li[0] = id;
}

template<int T>
__device__ __forceinline__ void merge4(const float* sv, const int* si, int t,
                                       float* dv, int* di) {
  float fv[T]; int fi[T];
  #pragma unroll
  for (int i = 0; i < T; ++i) { fv[i] = -FLT_MAX; fi[i] = 0x7fffffff; }
  for (int s = 0; s < 4; ++s)
    #pragma unroll
    for (int i = 0; i < T; ++i)
      topk_insert<T>(sv[(t*4+s)*T+i], si[(t*4+s)*T+i], fv, fi);
  #pragma unroll
  for (int i = 0; i < T; ++i) { dv[t*T+i] = fv[i]; di[t*T+i] = fi[i]; }
}

// ---------------- rowmap fill ---------------------------------------------
__global__ void fill_rowmap(int* rowmap, int n) {
  int i = blockIdx.x * blockDim.x + threadIdx.x;
  if (i < n) rowmap[i] = -1;
}

// -------- prep: softmax, normalize queries -> MFMA A-frag pack, updates ---
__global__ __launch_bounds__(384) void prep_kernel(
    const float* __restrict__ tf, const float* __restrict__ fc1,
    const float* __restrict__ fc2, const int* __restrict__ idx,
    const float* __restrict__ featm, const float* __restrict__ fc1m,
    const float* __restrict__ fc2m,
    short* __restrict__ Qp_feat, short* __restrict__ Qp_fc1, short* __restrict__ Qp_fc2,
    float* __restrict__ featU, float* __restrict__ fc1U, float* __restrict__ fc2U,
    int* __restrict__ rowmap)
{
  __shared__ float sbuf[8];
  const int b = blockIdx.x, t = threadIdx.x;
  const int trow = idx[b];
  const int qt = b >> 4, qr = b & 15;

  {
    float x = (t < DF) ? tf[b*DF + t] : 0.f;
    float ss = blockReduceSum(x*x, sbuf);
    float inv = 1.f / fmaxf(sqrtf(ss), EPSN);
    if (t < DF) {
      featU[b*DF + t] = 0.9f * featm[(size_t)trow*DF + t] + 0.1f * x;
      int ks = t >> 5, lg = (t >> 3) & 3, j = t & 7;
      int lane = qr + lg*16;
      union { __hip_bfloat16 h; short s; } cv;
      cv.h = __float2bfloat16(x * inv);
      Qp_feat[((qt*KSF + ks)*64 + lane)*8 + j] = cv.s;
    }
  }
  {
    float y = (t < CC) ? fc1[b*CC + t] : -FLT_MAX;
    float mx = blockReduceMax(y, sbuf);
    float e = (t < CC) ? expf(y - mx) : 0.f;
    float se = blockReduceSum(e, sbuf);
    float s = e / se;
    float s2 = blockReduceSum(s*s, sbuf);
    float inv2 = 1.f / fmaxf(sqrtf(s2), EPSN);
    if (t < CC) fc1U[b*CC + t] = 0.9f * fc1m[(size_t)trow*CC + t] + 0.1f * s;
    if (t < KSC*32) {
      int ks = t >> 5, lg = (t >> 3) & 3, j = t & 7;
      int lane = qr + lg*16;
      union { __hip_bfloat16 h; short s; } cv;
      cv.h = __float2bfloat16((t < CC) ? s * inv2 : 0.f);
      Qp_fc1[((qt*KSC + ks)*64 + lane)*8 + j] = cv.s;
    }
  }
  {
    float y = (t < CC) ? fc2[b*CC + t] : -FLT_MAX;
    float mx = blockReduceMax(y, sbuf);
    float e = (t < CC) ? expf(y - mx) : 0.f;
    float se = blockReduceSum(e, sbuf);
    float s = e / se;
    float s2 = blockReduceSum(s*s, sbuf);
    float inv2 = 1.f / fmaxf(sqrtf(s2), EPSN);
    if (t < CC) fc2U[b*CC + t] = 0.9f * fc2m[(size_t)trow*CC + t] + 0.1f * s;
    if (t < KSC*32) {
      int ks = t >> 5, lg = (t >> 3) & 3, j = t & 7;
      int lane = qr + lg*16;
      union { __hip_bfloat16 h; short s; } cv;
      cv.h = __float2bfloat16((t < CC) ? s * inv2 : 0.f);
      Qp_fc2[((qt*KSC + ks)*64 + lane)*8 + j] = cv.s;
    }
  }
  if (t == 0) rowmap[trow] = b;
}

// -------- dist v6: DMA staging + counted-vmcnt pipeline (T3/T4) -----------
// 2 tiles in flight per block; raw s_barrier keeps DMA alive across phases.
// Per-wave loads/tile: feat=4, fc=8 (wave0: 9).
template<int D, int KS, int T>
__global__ __launch_bounds__(256, 3) void dist_topk6(
    const float* __restrict__ bank, const float* __restrict__ ubank,
    const int* __restrict__ uids, const short8* __restrict__ Qp,
    float* __restrict__ cand_v, int* __restrict__ cand_i,
    int nmain, int ntq, int ntr)
{
  constexpr bool FEAT = (D == 256);
  constexpr int GROW = D * 4;                  // global row bytes: 1024/1380
  constexpr int SROW = FEAT ? 1024 : 1392;     // LDS row stride (16B mult)
  constexpr int BUFB = 16 * SROW;

  __shared__ __align__(16) char smem[2*BUFB + 128 + 2*64*17*4];
  char*  k344 = smem + 2*BUFB;                 // [2][16] f32 (fc k=344)
  float* sims = (float*)(smem + 2*BUFB + 128); // [2][64][17]
  float* mv   = (float*)smem;                  // epilogue alias
  int*   mi   = (int*)(smem + 256*T*4);

  const int t = threadIdx.x, l = t & 63, w = t >> 6;
  const int lc = l & 15, lg = l >> 4;
  const bool corr = ((int)blockIdx.x >= nmain);
  const float* srcb = corr ? ubank : bank;

  int tile0, nt;
  if (corr) { tile0 = blockIdx.x - nmain; nt = 1; }
  else {
    int b = blockIdx.x;
    tile0 = b*ntq + (b < ntr ? b : ntr);
    nt = ntq + (b < ntr ? 1 : 0);
  }

  short8 afr[KS];
  #pragma unroll
  for (int ks = 0; ks < KS; ++ks) afr[ks] = Qp[(w*KS + ks)*64 + l];

  auto STAGE = [&](int tile, int pn) {
    const char* tb = (const char*)srcb + (size_t)tile * (size_t)(16*GROW);
    char* bb = smem + pn*BUFB;
    #pragma unroll
    for (int r2 = 0; r2 < 4; ++r2) {
      int row = w*4 + r2;                      // wave-uniform
      if (FEAT) {
        // pre-swizzled source so swizzled reads see linear data (rule #21)
        gld16(tb + row*1024 + ((l ^ (row & 7)) * 16), bb + row*1024);
      } else {
        gld16(tb + row*1380 + l*16, bb + row*1392);
        if (l < 22) gld16(tb + row*1380 + 1024 + l*16, bb + row*1392 + 1024);
      }
    }
    if (!FEAT && w == 0 && l < 16)
      gld4(tb + l*1380 + 1376, k344 + pn*64);
  };

  STAGE(tile0, 0);
  if (nt > 1) STAGE(tile0 + 1, 1);

  float lv[T]; int li[T];
  #pragma unroll
  for (int i = 0; i < T; ++i) { lv[i] = -FLT_MAX; li[i] = 0x7fffffff; }

  for (int it = 0; it < nt; ++it) {
    const int pn = it & 1;

    // wait: tile it's loads complete; tile it+1 stays in flight
    if (it + 1 < nt) {
      if (FEAT) wait_vm4();
      else if (w == 0) wait_vm9();
      else wait_vm8();
    } else {
      wait_vm0();
    }
    raw_barrier();                             // all waves' portions landed

    const char* bb = smem + pn*BUFB;
    f32x4 acc = (f32x4){0.f, 0.f, 0.f, 0.f};
    float sq = 0.f;

    #pragma unroll
    for (int ks = 0; ks < KS; ++ks) {
      float v[8];
      if (!FEAT && ks == KS-1 && lg == 3) {    // fc tail: only k=344 valid
        v[0] = *(const float*)(k344 + pn*64 + lc*4);
        #pragma unroll
        for (int j = 1; j < 8; ++j) v[j] = 0.f;
      } else if (FEAT) {
        int g0 = ks*8 + lg*2;
        float4 a = *(const float4*)(bb + lc*1024 + ((g0 ^ (lc & 7)) * 16));
        float4 c = *(const float4*)(bb + lc*1024 + (((g0 + 1) ^ (lc & 7)) * 16));
        v[0]=a.x; v[1]=a.y; v[2]=a.z; v[3]=a.w;
        v[4]=c.x; v[5]=c.y; v[6]=c.z; v[7]=c.w;
      } else {
        const char* p = bb + lc*1392 + ks*128 + lg*32;
        float4 a = *(const float4*)p;
        float4 c = *(const float4*)(p + 16);
        v[0]=a.x; v[1]=a.y; v[2]=a.z; v[3]=a.w;
        v[4]=c.x; v[5]=c.y; v[6]=c.z; v[7]=c.w;
      }
      #pragma unroll
      for (int j = 0; j < 8; ++j) sq += v[j]*v[j];
      union { short8 s8; __hip_bfloat162 h2[4]; } fb;
      #pragma unroll
      for (int j = 0; j < 4; ++j)
        fb.h2[j] = __float22bfloat162_rn(make_float2(v[2*j], v[2*j+1]));
      acc = __builtin_amdgcn_mfma_f32_16x16x32_bf16(afr[ks], fb.s8, acc, 0, 0, 0);
    }

    // in-lane row rinv: lanes lc, lc^16, lc^32, lc^48 hold k-slice partials
    float s = sq;
    s += __shfl_xor(s, 16);
    s += __shfl_xor(s, 32);
    float ri = 1.f / fmaxf(sqrtf(s), EPSN);

    float* sp = sims + pn*64*17;
    #pragma unroll
    for (int rg = 0; rg < 4; ++rg)
      sp[(w*16 + lg*4 + rg)*17 + lc] = acc[rg] * ri;

    wait_lgkm0();                              // sims writes visible
    raw_barrier();                             // bb[pn] reads done everywhere

    if (it + 2 < nt) STAGE(tile0 + it + 2, pn);  // refill the buffer just freed

    // topk: 4 threads per query, 4 rows each
    {
      int q = t & 63, sub = t >> 6;
      const float* s2 = sims + pn*64*17 + q*17 + sub*4;
      #pragma unroll
      for (int j = 0; j < 4; ++j) {
        int r = sub*4 + j;
        int id = corr ? (uids[tile0*16 + r] | FRESH) : ((tile0 + it)*16 + r);
        topk_insert<T>(s2[j], id, lv, li);
      }
    }
  }
  __syncthreads();                             // full drain before alias

  // block merge: 4 sublists per query -> block-major coalesced cand slot
  #pragma unroll
  for (int i = 0; i < T; ++i) { mv[t*T + i] = lv[i]; mi[t*T + i] = li[i]; }
  __syncthreads();
  if (t < 64) {
    float fv[T]; int fi[T];
    #pragma unroll
    for (int i = 0; i < T; ++i) { fv[i] = -FLT_MAX; fi[i] = 0x7fffffff; }
    for (int s = 0; s < 4; ++s) {
      int srcidx = t + 64*s;
      #pragma unroll
      for (int i = 0; i < T; ++i)
        topk_insert<T>(mv[srcidx*T + i], mi[srcidx*T + i], fv, fi);
    }
    size_t base = ((size_t)blockIdx.x*64 + t)*T;
    #pragma unroll
    for (int i = 0; i < T; ++i) { cand_v[base + i] = fv[i]; cand_i[base + i] = fi[i]; }
  }
}

// -------- merge stage 1: 8 blocks/query; filters stale updated rows -------
template<int T>
__global__ __launch_bounds__(256) void merge_stage1(
    const float* __restrict__ cv, const int* __restrict__ ci,
    const int* __restrict__ rowmap, int nslots,
    float* __restrict__ midv, int* __restrict__ midi)
{
  __shared__ float sv[256*T]; __shared__ int si[256*T];
  __shared__ float sv2[64*T]; __shared__ int si2[64*T];
  const int q = blockIdx.x >> 3, s = blockIdx.x & 7, t = threadIdx.x;
  const int len = (nslots + 7) >> 3;
  const int lo = s*len, hi = min(nslots, lo + len);
  float lv[T]; int li[T];
  #pragma unroll
  for (int i = 0; i < T; ++i) { lv[i] = -FLT_MAX; li[i] = 0x7fffffff; }
  for (int c = lo + t; c < hi; c += 256) {
    size_t base = ((size_t)c*64 + q)*T;
    #pragma unroll
    for (int i = 0; i < T; ++i) {
      int id = ci[base + i];
      if ((id & FRESH) || rowmap[id] < 0)
        topk_insert<T>(cv[base + i], id, lv, li);
    }
  }
  #pragma unroll
  for (int i = 0; i < T; ++i) { sv[t*T+i] = lv[i]; si[t*T+i] = li[i]; }
  __syncthreads();
  if (t < 64) merge4<T>(sv, si, t, sv2, si2);
  __syncthreads();
  if (t < 16) merge4<T>(sv2, si2, t, sv, si);
  __syncthreads();
  if (t < 4)  merge4<T>(sv, si, t, sv2, si2);
  __syncthreads();
  if (t == 0) {
    float fv[T]; int fi[T];
    #pragma unroll
    for (int i = 0; i < T; ++i) { fv[i] = -FLT_MAX; fi[i] = 0x7fffffff; }
    for (int c = 0; c < 4*T; ++c) topk_insert<T>(sv2[c], si2[c], fv, fi);
    #pragma unroll
    for (int i = 0; i < T; ++i) {
      midv[blockIdx.x*T + i] = fv[i];
      midi[blockIdx.x*T + i] = fi[i];
    }
  }
}

// -------- merge stage 2: final top-T per query (strip FRESH flag) ---------
template<int T>
__global__ __launch_bounds__(64) void merge_stage2(
    const float* __restrict__ midv, const int* __restrict__ midi,
    int* __restrict__ topout)      // stride 6
{
  __shared__ float sv[8*T]; __shared__ int si[8*T];
  const int q = blockIdx.x, t = threadIdx.x;
  if (t < 8*T) { sv[t] = midv[q*8*T + t]; si[t] = midi[q*8*T + t]; }
  __syncthreads();
  if (t == 0) {
    float fv[T]; int fi[T];
    #pragma unroll
    for (int i = 0; i < T; ++i) { fv[i] = -FLT_MAX; fi[i] = 0x7fffffff; }
    for (int c = 0; c < 8*T; ++c) topk_insert<T>(sv[c], si[c], fv, fi);
    #pragma unroll
    for (int i = 0; i < T; ++i) topout[q*6 + i] = fi[i] & ~FRESH;
  }
}

// ---------------- losses ---------------------------------------------------
__global__ __launch_bounds__(384) void loss_softmax_kernel(
    const int* __restrict__ topfeat, const int* __restrict__ rowmap,
    const float* __restrict__ fc1m, const float* __restrict__ fc1U,
    const float* __restrict__ fc2m, const float* __restrict__ fc2U,
    float* __restrict__ out)
{
  __shared__ float sbuf[8];
  int p = blockIdx.x;                // 0..319
  int q = p / 5, j = p % 5 + 1;
  int row = topfeat[q*6 + j];
  int u = rowmap[row];
  const float* r1 = (u >= 0) ? (fc1U + (size_t)u * CC) : (fc1m + (size_t)row * CC);
  const float* r2 = (u >= 0) ? (fc2U + (size_t)u * CC) : (fc2m + (size_t)row * CC);
  int t = threadIdx.x;
  float v = (t < CC) ? fabsf(r1[t] - r2[t]) : 0.f;
  float s = blockReduceSum(v, sbuf);
  if (t == 0) atomicAdd(out, s * (1.f / (320.f * 345.f)));
}

__global__ __launch_bounds__(256) void loss_feature_kernel(
    const int* __restrict__ topfc1, const int* __restrict__ topfc2,
    const int* __restrict__ rowmap, const float* __restrict__ featm,
    const float* __restrict__ featU, float* __restrict__ out)
{
  __shared__ float sbuf[8];
  int p = blockIdx.x;                // 0..255
  int q = p / 4, j = p % 4 + 1;
  int ra = topfc1[q*6 + j], rb = topfc2[q*6 + j];
  int ua = rowmap[ra], ub = rowmap[rb];
  const float* A  = (ua >= 0) ? (featU + (size_t)ua * DF) : (featm + (size_t)ra * DF);
  const float* Bp = (ub >= 0) ? (featU + (size_t)ub * DF) : (featm + (size_t)rb * DF);
  int t = threadIdx.x;               // 256 == DF
  float a = A[t], b = Bp[t];
  float saa = blockReduceSum(a*a, sbuf);
  float sbb = blockReduceSum(b*b, sbuf);
  float sab = blockReduceSum(a*b, sbuf);
  if (t == 0) {
    float fd = 0.5f * (1.f - sab / (fmaxf(sqrtf(saa), EPSN) * fmaxf(sqrtf(sbb), EPSN)));
    atomicAdd(out + 1, fd * (1.f / 256.f));
  }
}

// ---------------- launch ---------------------------------------------------
extern "C" void kernel_launch(void* const* d_in, const int* in_sizes, int n_in,
                              void* d_out, int out_size, void* d_ws, size_t ws_size,
                              hipStream_t stream)
{
  const float* tf    = (const float*)d_in[0];
  const float* fc1   = (const float*)d_in[1];
  const float* fc2   = (const float*)d_in[2];
  const int*   idx   = (const int*)d_in[3];
  const float* featm = (const float*)d_in[4];
  const float* fc1m  = (const float*)d_in[5];
  const float* fc2m  = (const float*)d_in[6];
  float* out = (float*)d_out;

  const int N     = in_sizes[4] / DF;    // 200000
  const int TILES = N / 16;              // 12500
  const int NTQ   = TILES / NBM;         // 16
  const int NTR   = TILES - NTQ * NBM;   // 212
  const int NSLOT = NBM + 4;             // + 4 updated-row blocks

  char* w = (char*)d_ws;
  auto alloc = [&](size_t bytes) {
    char* p = w;
    w += (bytes + 255) & ~(size_t)255;
    return (void*)p;
  };
  short* Qp_feat = (short*)alloc((size_t)4 * KSF * 64 * 8 * 2);
  short* Qp_fc1  = (short*)alloc((size_t)4 * KSC * 64 * 8 * 2);
  short* Qp_fc2  = (short*)alloc((size_t)4 * KSC * 64 * 8 * 2);
  float* featU   = (float*)alloc((size_t)NQ * DF * 4);
  float* fc1U    = (float*)alloc((size_t)NQ * CC * 4);
  float* fc2U    = (float*)alloc((size_t)NQ * CC * 4);
  int*   rowmap  = (int*)alloc((size_t)N * 4);
  int*   topfeat = (int*)alloc(NQ * 6 * 4);
  int*   topfc1  = (int*)alloc(NQ * 6 * 4);
  int*   topfc2  = (int*)alloc(NQ * 6 * 4);
  float* cand_v  = (float*)alloc((size_t)NSLOT * 64 * 6 * 4);
  int*   cand_i  = (int*)alloc((size_t)NSLOT * 64 * 6 * 4);
  float* midv    = (float*)alloc((size_t)NQ * 8 * 6 * 4);
  int*   midi    = (int*)alloc((size_t)NQ * 8 * 6 * 4);

  zero_out<<<1, 64, 0, stream>>>(out);
  fill_rowmap<<<(N + 255) / 256, 256, 0, stream>>>(rowmap, N);
  prep_kernel<<<NQ, 384, 0, stream>>>(tf, fc1, fc2, idx, featm, fc1m, fc2m,
      Qp_feat, Qp_fc1, Qp_fc2, featU, fc1U, fc2U, rowmap);

  // feature: top-6 (drop first, keep 5)
  dist_topk6<DF, KSF, 6><<<NSLOT, 256, 0, stream>>>(
      featm, featU, idx, (const short8*)Qp_feat, cand_v, cand_i, NBM, NTQ, NTR);
  merge_stage1<6><<<NQ*8, 256, 0, stream>>>(cand_v, cand_i, rowmap, NSLOT, midv, midi);
  merge_stage2<6><<<NQ, 64, 0, stream>>>(midv, midi, topfeat);

  // fc1: top-5 (drop first, keep 4)
  dist_topk6<CC, KSC, 5><<<NSLOT, 256, 0, stream>>>(
      fc1m, fc1U, idx, (const short8*)Qp_fc1, cand_v, cand_i, NBM, NTQ, NTR);
  merge_stage1<5><<<NQ*8, 256, 0, stream>>>(cand_v, cand_i, rowmap, NSLOT, midv, midi);
  merge_stage2<5><<<NQ, 64, 0, stream>>>(midv, midi, topfc1);

  // fc2: top-5
  dist_topk6<CC, KSC, 5><<<NSLOT, 256, 0, stream>>>(
      fc2m, fc2U, idx, (const short8*)Qp_fc2, cand_v, cand_i, NBM, NTQ, NTR);
  merge_stage1<5><<<NQ*8, 256, 0, stream>>>(cand_v, cand_i, rowmap, NSLOT, midv, midi);
  merge_stage2<5><<<NQ, 64, 0, stream>>>(midv, midi, topfc2);

  loss_softmax_kernel<<<320, 384, 0, stream>>>(topfeat, rowmap, fc1m, fc1U, fc2m, fc2U, out);
  loss_feature_kernel<<<256, 256, 0, stream>>>(topfc1, topfc2, rowmap, featm, featU, out);
}